// Round 1
// baseline (299.779 us; speedup 1.0000x reference)
//
#include <hip/hip_runtime.h>

typedef unsigned short u16;
typedef unsigned int u32;
typedef __bf16 bf16x8_t __attribute__((ext_vector_type(8)));
typedef float f32x4 __attribute__((ext_vector_type(4)));

__device__ __forceinline__ u16 f2b(float f) {
  union { float f; u32 u; } v; v.f = f;
  u32 r = v.u + 0x7fffu + ((v.u >> 16) & 1u);
  return (u16)(r >> 16);
}

__device__ __forceinline__ f32x4 mfma16(uint4 a, uint4 b, f32x4 c) {
  return __builtin_amdgcn_mfma_f32_16x16x32_bf16(
      __builtin_bit_cast(bf16x8_t, a), __builtin_bit_cast(bf16x8_t, b), c, 0, 0, 0);
}

// ---------------- weight convert + transpose: W[K,N] f32 -> Wt[N,K] bf16 ----
__global__ void convT_k(const float* __restrict__ w, u16* __restrict__ wt,
                        int K, int N) {
  int idx = blockIdx.x * 256 + threadIdx.x;
  if (idx >= K * N) return;
  int kk = idx / N, n = idx - kk * N;
  wt[(size_t)n * K + kk] = f2b(w[idx]);
}

// ---------------- LayerNorm: rows of 384 f32 -> bf16 ------------------------
__global__ __launch_bounds__(256) void ln_k(const float* __restrict__ x,
                                            const float* __restrict__ g,
                                            const float* __restrict__ bta,
                                            u16* __restrict__ out) {
  int lane = threadIdx.x & 63, wid = threadIdx.x >> 6;
  int row = blockIdx.x * 4 + wid;
  const float* xr = x + (size_t)row * 384;
  float v[6];
  float s = 0.f;
#pragma unroll
  for (int i = 0; i < 6; i++) { v[i] = xr[i * 64 + lane]; s += v[i]; }
#pragma unroll
  for (int off = 32; off >= 1; off >>= 1) s += __shfl_xor(s, off);
  float mean = s * (1.0f / 384.0f);
  float vs = 0.f;
#pragma unroll
  for (int i = 0; i < 6; i++) { float d = v[i] - mean; vs += d * d; }
#pragma unroll
  for (int off = 32; off >= 1; off >>= 1) vs += __shfl_xor(vs, off);
  float rstd = rsqrtf(vs * (1.0f / 384.0f) + 1e-5f);
  u16* orow = out + (size_t)row * 384;
#pragma unroll
  for (int i = 0; i < 6; i++) {
    int c = i * 64 + lane;
    orow[c] = f2b((v[i] - mean) * rstd * g[c] + bta[c]);
  }
}

// ---------------- GEMM: A[M,K]bf16 @ Bt[N,K]bf16^T, fp32 accum --------------
// EPI 0: out f32 = acc + bias + res      (proj, fc2)
// EPI 1: out bf16 = gelu(acc + bias)     (fc1)
// EPI 2: qkv scatter: q scaled, k, v transposed
#define BM 128
#define BN 64
#define BKT 64

template <int EPI>
__global__ __launch_bounds__(256) void gemm_k(
    const u16* __restrict__ A, const u16* __restrict__ Bt,
    const float* __restrict__ bias, const float* __restrict__ res,
    void* __restrict__ outp, int M, int Nn, int K,
    u16* __restrict__ qp, u16* __restrict__ kp, u16* __restrict__ vtp) {
  __shared__ __align__(16) u16 As[BM * BKT];
  __shared__ __align__(16) u16 Bs[BN * BKT];
  int tid = threadIdx.x;
  int lane = tid & 63, wid = tid >> 6;
  int li = lane & 15, lg = lane >> 4;
  int wr = wid >> 1, wc = wid & 1;
  int row0 = blockIdx.y * BM, col0 = blockIdx.x * BN;

  f32x4 z = {0.f, 0.f, 0.f, 0.f};
  f32x4 acc[4][2];
#pragma unroll
  for (int m = 0; m < 4; m++)
#pragma unroll
    for (int n = 0; n < 2; n++) acc[m][n] = z;

  for (int k0 = 0; k0 < K; k0 += BKT) {
#pragma unroll
    for (int i = 0; i < 4; i++) {  // A tile: 128 rows x 8 chunks(16B)
      int cid = i * 256 + tid;
      int r = cid >> 3, cc = cid & 7;
      uint4 d = *(const uint4*)(A + (size_t)(row0 + r) * K + k0 + cc * 8);
      *(uint4*)((char*)As + r * 128 + ((cc * 16) ^ ((r & 7) << 4))) = d;
    }
#pragma unroll
    for (int i = 0; i < 2; i++) {  // B tile: 64 rows x 8 chunks
      int cid = i * 256 + tid;
      int r = cid >> 3, cc = cid & 7;
      uint4 d = *(const uint4*)(Bt + (size_t)(col0 + r) * K + k0 + cc * 8);
      *(uint4*)((char*)Bs + r * 128 + ((cc * 16) ^ ((r & 7) << 4))) = d;
    }
    __syncthreads();
#pragma unroll
    for (int kk = 0; kk < 2; kk++) {
      uint4 af[4], bf[2];
#pragma unroll
      for (int m = 0; m < 4; m++) {
        int r = wr * 64 + m * 16 + li;
        af[m] = *(const uint4*)((const char*)As + r * 128 +
                                ((kk * 64 + lg * 16) ^ ((r & 7) << 4)));
      }
#pragma unroll
      for (int n = 0; n < 2; n++) {
        int c = wc * 32 + n * 16 + li;
        bf[n] = *(const uint4*)((const char*)Bs + c * 128 +
                                ((kk * 64 + lg * 16) ^ ((c & 7) << 4)));
      }
#pragma unroll
      for (int m = 0; m < 4; m++)
#pragma unroll
        for (int n = 0; n < 2; n++)
          acc[m][n] = mfma16(af[m], bf[n], acc[m][n]);
    }
    __syncthreads();
  }

#pragma unroll
  for (int m = 0; m < 4; m++) {
#pragma unroll
    for (int n = 0; n < 2; n++) {
#pragma unroll
      for (int j = 0; j < 4; j++) {
        int r = row0 + wr * 64 + m * 16 + lg * 4 + j;
        int c = col0 + wc * 32 + n * 16 + li;
        float v = acc[m][n][j] + bias[c];
        if (EPI == 0) {
          ((float*)outp)[(size_t)r * Nn + c] = v + res[(size_t)r * Nn + c];
        } else if (EPI == 1) {
          float gl = 0.5f * v * (1.0f + erff(v * 0.70710678118f));
          ((u16*)outp)[(size_t)r * Nn + c] = f2b(gl);
        } else {
          int t = c / 384;                 // uniform per block (384 = 6*64)
          int c2 = c - t * 384;
          int hh = c2 >> 6, d = c2 & 63;
          int b = r >> 11, nn = r & 2047;
          size_t bh = (size_t)b * 6 + hh;
          if (t == 0)      qp[(bh * 2048 + nn) * 64 + d] = f2b(v * 0.125f);
          else if (t == 1) kp[(bh * 2048 + nn) * 64 + d] = f2b(v);
          else             vtp[(bh * 64 + d) * 2048 + nn] = f2b(v);
        }
      }
    }
  }
}

// ---------------- flash attention: 1 wave, 16 q-rows / block ----------------
// q[BH,N,D] (pre-scaled), k[BH,N,D], vt[BH,D,N]; out bf16 [B,N,C]
__global__ __launch_bounds__(64) void attn_k(const u16* __restrict__ q,
                                             const u16* __restrict__ k,
                                             const u16* __restrict__ vt,
                                             u16* __restrict__ out) {
  __shared__ __align__(16) u16 Pl[16 * 32];
  int lane = threadIdx.x;
  int li = lane & 15, lg = lane >> 4;
  int bh = blockIdx.y;
  int b = bh / 6, hh = bh - b * 6;
  int qb = blockIdx.x * 16;
  const u16* qbase = q + ((size_t)bh * 2048 + qb) * 64;
  const u16* kbase = k + (size_t)bh * 2048 * 64;
  const u16* vbase = vt + (size_t)bh * 64 * 2048;

  uint4 qf[2];
#pragma unroll
  for (int f = 0; f < 2; f++)
    qf[f] = *(const uint4*)(qbase + (size_t)li * 64 + f * 32 + lg * 8);

  f32x4 z = {0.f, 0.f, 0.f, 0.f};
  f32x4 o[4];
#pragma unroll
  for (int i = 0; i < 4; i++) o[i] = z;
  float mrun[4], lsum[4];
#pragma unroll
  for (int j = 0; j < 4; j++) { mrun[j] = -1e30f; lsum[j] = 0.f; }

  for (int kb = 0; kb < 2048; kb += 32) {
    f32x4 s0 = z, s1 = z;
#pragma unroll
    for (int f = 0; f < 2; f++) {
      uint4 kf0 = *(const uint4*)(kbase + (size_t)(kb + li) * 64 + f * 32 + lg * 8);
      uint4 kf1 = *(const uint4*)(kbase + (size_t)(kb + 16 + li) * 64 + f * 32 + lg * 8);
      s0 = mfma16(qf[f], kf0, s0);
      s1 = mfma16(qf[f], kf1, s1);
    }
    float tm[4], rs[4], al[4];
#pragma unroll
    for (int j = 0; j < 4; j++) tm[j] = fmaxf(s0[j], s1[j]);
#pragma unroll
    for (int off = 8; off >= 1; off >>= 1)
#pragma unroll
      for (int j = 0; j < 4; j++) tm[j] = fmaxf(tm[j], __shfl_xor(tm[j], off));
#pragma unroll
    for (int j = 0; j < 4; j++) {
      float mn = fmaxf(mrun[j], tm[j]);
      al[j] = __expf(mrun[j] - mn);
      mrun[j] = mn;
      float p0 = __expf(s0[j] - mn);
      float p1 = __expf(s1[j] - mn);
      rs[j] = p0 + p1;
      Pl[(lg * 4 + j) * 32 + li] = f2b(p0);
      Pl[(lg * 4 + j) * 32 + 16 + li] = f2b(p1);
    }
#pragma unroll
    for (int off = 8; off >= 1; off >>= 1)
#pragma unroll
      for (int j = 0; j < 4; j++) rs[j] += __shfl_xor(rs[j], off);
#pragma unroll
    for (int j = 0; j < 4; j++) lsum[j] = lsum[j] * al[j] + rs[j];
    __syncthreads();
    uint4 pa = *(const uint4*)((const char*)Pl + li * 64 + lg * 16);
#pragma unroll
    for (int db = 0; db < 4; db++) {
      uint4 vf = *(const uint4*)(vbase + (size_t)(db * 16 + li) * 2048 + kb + lg * 8);
#pragma unroll
      for (int j = 0; j < 4; j++) o[db][j] *= al[j];
      o[db] = mfma16(pa, vf, o[db]);
    }
    __syncthreads();
  }
#pragma unroll
  for (int db = 0; db < 4; db++)
#pragma unroll
    for (int j = 0; j < 4; j++) {
      float v = o[db][j] / lsum[j];
      out[(size_t)(b * 2048 + qb + lg * 4 + j) * 384 + hh * 64 + db * 16 + li] =
          f2b(v);
    }
}

// ---------------------------------------------------------------------------
extern "C" void kernel_launch(void* const* d_in, const int* in_sizes, int n_in,
                              void* d_out, int out_size, void* d_ws,
                              size_t ws_size, hipStream_t stream) {
  const float* x      = (const float*)d_in[0];
  const float* ln1_g  = (const float*)d_in[1];
  const float* ln1_b  = (const float*)d_in[2];
  const float* qkv_w  = (const float*)d_in[3];
  const float* qkv_b  = (const float*)d_in[4];
  const float* proj_w = (const float*)d_in[5];
  const float* proj_b = (const float*)d_in[6];
  const float* ln2_g  = (const float*)d_in[7];
  const float* ln2_b  = (const float*)d_in[8];
  const float* fc1_w  = (const float*)d_in[9];
  const float* fc1_b  = (const float*)d_in[10];
  const float* fc2_w  = (const float*)d_in[11];
  const float* fc2_b  = (const float*)d_in[12];
  float* out = (float*)d_out;

  char* p = (char*)d_ws;
  u16* qkvwt  = (u16*)p;  p += (size_t)1152 * 384 * 2;
  u16* projwt = (u16*)p;  p += (size_t)384 * 384 * 2;
  u16* fc1wt  = (u16*)p;  p += (size_t)1536 * 384 * 2;
  u16* fc2wt  = (u16*)p;  p += (size_t)384 * 1536 * 2;
  float* x1   = (float*)p; p += (size_t)8192 * 384 * 4;
  u16* reg1   = (u16*)p;  p += (size_t)8192 * 384 * 2;   // h1 -> aout -> h2
  u16* reg2   = (u16*)p;  p += (size_t)8192 * 1536 * 2;  // q,k,vt -> h3
  u16* qd  = reg2;
  u16* kd  = reg2 + (size_t)24 * 2048 * 64;
  u16* vtd = kd + (size_t)24 * 2048 * 64;
  u16* h3  = reg2;

  convT_k<<<(384 * 1152 + 255) / 256, 256, 0, stream>>>(qkv_w, qkvwt, 384, 1152);
  convT_k<<<(384 * 384 + 255) / 256, 256, 0, stream>>>(proj_w, projwt, 384, 384);
  convT_k<<<(384 * 1536 + 255) / 256, 256, 0, stream>>>(fc1_w, fc1wt, 384, 1536);
  convT_k<<<(1536 * 384 + 255) / 256, 256, 0, stream>>>(fc2_w, fc2wt, 1536, 384);

  ln_k<<<2048, 256, 0, stream>>>(x, ln1_g, ln1_b, reg1);
  gemm_k<2><<<dim3(1152 / BN, 8192 / BM), 256, 0, stream>>>(
      reg1, qkvwt, qkv_b, nullptr, nullptr, 8192, 1152, 384, qd, kd, vtd);
  attn_k<<<dim3(128, 24), 64, 0, stream>>>(qd, kd, vtd, reg1);
  gemm_k<0><<<dim3(384 / BN, 8192 / BM), 256, 0, stream>>>(
      reg1, projwt, proj_b, x, x1, 8192, 384, 384, nullptr, nullptr, nullptr);
  ln_k<<<2048, 256, 0, stream>>>(x1, ln2_g, ln2_b, reg1);
  gemm_k<1><<<dim3(1536 / BN, 8192 / BM), 256, 0, stream>>>(
      reg1, fc1wt, fc1_b, nullptr, h3, 8192, 1536, 384, nullptr, nullptr, nullptr);
  gemm_k<0><<<dim3(384 / BN, 8192 / BM), 256, 0, stream>>>(
      h3, fc2wt, fc2_b, x1, out, 8192, 384, 1536, nullptr, nullptr, nullptr);
}

// Round 2
// 213.636 us; speedup vs baseline: 1.4032x; 1.4032x over previous
//
#include <hip/hip_runtime.h>

typedef unsigned short u16;
typedef unsigned int u32;
typedef __bf16 bf16x8_t __attribute__((ext_vector_type(8)));
typedef float f32x4 __attribute__((ext_vector_type(4)));

__device__ __forceinline__ u16 f2b(float f) {
  union { float f; u32 u; } v; v.f = f;
  u32 r = v.u + 0x7fffu + ((v.u >> 16) & 1u);
  return (u16)(r >> 16);
}

__device__ __forceinline__ f32x4 mfma16(uint4 a, uint4 b, f32x4 c) {
  return __builtin_amdgcn_mfma_f32_16x16x32_bf16(
      __builtin_bit_cast(bf16x8_t, a), __builtin_bit_cast(bf16x8_t, b), c, 0, 0, 0);
}

__device__ __forceinline__ void load_lds16(const void* g, void* l) {
  __builtin_amdgcn_global_load_lds(
      (const __attribute__((address_space(1))) unsigned int*)g,
      (__attribute__((address_space(3))) unsigned int*)l, 16, 0, 0);
}

// ---------------- weight convert + transpose: W[K,N] f32 -> Wt[N,K] bf16 ----
__global__ void convT_k(const float* __restrict__ w, u16* __restrict__ wt,
                        int K, int N) {
  int idx = blockIdx.x * 256 + threadIdx.x;
  if (idx >= K * N) return;
  int kk = idx / N, n = idx - kk * N;
  wt[(size_t)n * K + kk] = f2b(w[idx]);
}

// ---------------- LayerNorm: rows of 384 f32 -> bf16 ------------------------
__global__ __launch_bounds__(256) void ln_k(const float* __restrict__ x,
                                            const float* __restrict__ g,
                                            const float* __restrict__ bta,
                                            u16* __restrict__ out) {
  int lane = threadIdx.x & 63, wid = threadIdx.x >> 6;
  int row = blockIdx.x * 4 + wid;
  const float* xr = x + (size_t)row * 384;
  float v[6];
  float s = 0.f;
#pragma unroll
  for (int i = 0; i < 6; i++) { v[i] = xr[i * 64 + lane]; s += v[i]; }
#pragma unroll
  for (int off = 32; off >= 1; off >>= 1) s += __shfl_xor(s, off);
  float mean = s * (1.0f / 384.0f);
  float vs = 0.f;
#pragma unroll
  for (int i = 0; i < 6; i++) { float d = v[i] - mean; vs += d * d; }
#pragma unroll
  for (int off = 32; off >= 1; off >>= 1) vs += __shfl_xor(vs, off);
  float rstd = rsqrtf(vs * (1.0f / 384.0f) + 1e-5f);
  u16* orow = out + (size_t)row * 384;
#pragma unroll
  for (int i = 0; i < 6; i++) {
    int c = i * 64 + lane;
    orow[c] = f2b((v[i] - mean) * rstd * g[c] + bta[c]);
  }
}

// ---------------- GEMM: A[M,K]bf16 @ Bt[N,K]bf16^T, fp32 accum --------------
#define BM 128
#define BN 64
#define BKT 64

template <int EPI>
__global__ __launch_bounds__(256) void gemm_k(
    const u16* __restrict__ A, const u16* __restrict__ Bt,
    const float* __restrict__ bias, const float* __restrict__ res,
    void* __restrict__ outp, int M, int Nn, int K,
    u16* __restrict__ qp, u16* __restrict__ kp, u16* __restrict__ vtp) {
  __shared__ __align__(16) u16 As[BM * BKT];
  __shared__ __align__(16) u16 Bs[BN * BKT];
  int tid = threadIdx.x;
  int lane = tid & 63, wid = tid >> 6;
  int li = lane & 15, lg = lane >> 4;
  int wr = wid >> 1, wc = wid & 1;
  int row0 = blockIdx.y * BM, col0 = blockIdx.x * BN;

  f32x4 z = {0.f, 0.f, 0.f, 0.f};
  f32x4 acc[4][2];
#pragma unroll
  for (int m = 0; m < 4; m++)
#pragma unroll
    for (int n = 0; n < 2; n++) acc[m][n] = z;

  for (int k0 = 0; k0 < K; k0 += BKT) {
#pragma unroll
    for (int i = 0; i < 4; i++) {  // A tile: 128 rows x 8 chunks(16B)
      int cid = i * 256 + tid;
      int r = cid >> 3, cc = cid & 7;
      uint4 d = *(const uint4*)(A + (size_t)(row0 + r) * K + k0 + cc * 8);
      *(uint4*)((char*)As + r * 128 + ((cc * 16) ^ ((r & 7) << 4))) = d;
    }
#pragma unroll
    for (int i = 0; i < 2; i++) {  // B tile: 64 rows x 8 chunks
      int cid = i * 256 + tid;
      int r = cid >> 3, cc = cid & 7;
      uint4 d = *(const uint4*)(Bt + (size_t)(col0 + r) * K + k0 + cc * 8);
      *(uint4*)((char*)Bs + r * 128 + ((cc * 16) ^ ((r & 7) << 4))) = d;
    }
    __syncthreads();
#pragma unroll
    for (int kk = 0; kk < 2; kk++) {
      uint4 af[4], bf[2];
#pragma unroll
      for (int m = 0; m < 4; m++) {
        int r = wr * 64 + m * 16 + li;
        af[m] = *(const uint4*)((const char*)As + r * 128 +
                                ((kk * 64 + lg * 16) ^ ((r & 7) << 4)));
      }
#pragma unroll
      for (int n = 0; n < 2; n++) {
        int c = wc * 32 + n * 16 + li;
        bf[n] = *(const uint4*)((const char*)Bs + c * 128 +
                                ((kk * 64 + lg * 16) ^ ((c & 7) << 4)));
      }
#pragma unroll
      for (int m = 0; m < 4; m++)
#pragma unroll
        for (int n = 0; n < 2; n++)
          acc[m][n] = mfma16(af[m], bf[n], acc[m][n]);
    }
    __syncthreads();
  }

#pragma unroll
  for (int m = 0; m < 4; m++) {
#pragma unroll
    for (int n = 0; n < 2; n++) {
#pragma unroll
      for (int j = 0; j < 4; j++) {
        int r = row0 + wr * 64 + m * 16 + lg * 4 + j;
        int c = col0 + wc * 32 + n * 16 + li;
        float v = acc[m][n][j] + bias[c];
        if (EPI == 0) {
          ((float*)outp)[(size_t)r * Nn + c] = v + res[(size_t)r * Nn + c];
        } else if (EPI == 1) {
          float gl = 0.5f * v * (1.0f + erff(v * 0.70710678118f));
          ((u16*)outp)[(size_t)r * Nn + c] = f2b(gl);
        } else {
          int t = c / 384;                 // uniform per block (384 = 6*64)
          int c2 = c - t * 384;
          int hh = c2 >> 6, d = c2 & 63;
          int b = r >> 11, nn = r & 2047;
          size_t bh = (size_t)b * 6 + hh;
          if (t == 0)      qp[(bh * 2048 + nn) * 64 + d] = f2b(v * 0.125f);
          else if (t == 1) kp[(bh * 2048 + nn) * 64 + d] = f2b(v);
          else             vtp[(bh * 64 + d) * 2048 + nn] = f2b(v);
        }
      }
    }
  }
}

// ---------------- flash attention: 4 waves, 64 q-rows / block ---------------
// q[BH,N,D] (pre-scaled), k[BH,N,D], vt[BH,D,N]; out bf16 [B,N,C]
// LDS: K,V tiles (64kv x 64d) double-buffered, XOR-swizzled; P per wave.
__global__ __launch_bounds__(256) void attn_k(const u16* __restrict__ q,
                                              const u16* __restrict__ k,
                                              const u16* __restrict__ vt,
                                              u16* __restrict__ out) {
  __shared__ __align__(16) u16 Ks[2][64 * 64];   // [kv][d], swz byte^((kv&7)<<4)
  __shared__ __align__(16) u16 Vs[2][64 * 64];   // [d][kv], swz byte^((d&7)<<4)
  __shared__ __align__(16) u16 Ps[4][16 * 64];   // per wave [q][kv], swz ((q&7)<<4)

  int tid = threadIdx.x;
  int lane = tid & 63, wid = tid >> 6;
  int li = lane & 15, lg = lane >> 4;
  int bh = blockIdx.y;
  int b = bh / 6, hh = bh - b * 6;
  int qb = blockIdx.x * 64 + wid * 16;

  const u16* qbase = q + ((size_t)bh * 2048 + qb) * 64;
  const char* kbase = (const char*)(k + (size_t)bh * 2048 * 64);
  const char* vbase = (const char*)(vt + (size_t)bh * 64 * 2048);
  char* Pw = (char*)Ps[wid];

  // staging geometry (per lane)
  int r8 = lane >> 3;               // 0..7 : row within 8-row chunk
  int cb = (lane & 7) << 4;         // byte col 0..112
  int swz = r8 << 4;
  int ck0 = wid * 2;                // this wave's chunks: ck0, ck0+1

  uint4 qf[2];
#pragma unroll
  for (int f = 0; f < 2; f++)
    qf[f] = *(const uint4*)(qbase + (size_t)li * 64 + f * 32 + lg * 8);

  f32x4 z = {0.f, 0.f, 0.f, 0.f};
  f32x4 o[4];
#pragma unroll
  for (int i = 0; i < 4; i++) o[i] = z;
  float mrun[4], lsum[4];
#pragma unroll
  for (int j = 0; j < 4; j++) { mrun[j] = -1e30f; lsum[j] = 0.f; }

  // prologue: stage tile 0 into buf 0
#pragma unroll
  for (int i = 0; i < 2; i++) {
    int chunk = ck0 + i;
    load_lds16(kbase + (size_t)(chunk * 8 + r8) * 128 + (cb ^ swz),
               (char*)Ks[0] + chunk * 1024);
    load_lds16(vbase + (size_t)(chunk * 8 + r8) * 4096 + (cb ^ swz),
               (char*)Vs[0] + chunk * 1024);
  }
  asm volatile("s_waitcnt vmcnt(0)");
  __syncthreads();

  int buf = 0;
  for (int t = 0; t < 32; t++) {
    // issue next tile's staging loads
    if (t + 1 < 32) {
      int kv0 = (t + 1) * 64;
#pragma unroll
      for (int i = 0; i < 2; i++) {
        int chunk = ck0 + i;
        load_lds16(kbase + (size_t)(kv0 + chunk * 8 + r8) * 128 + (cb ^ swz),
                   (char*)Ks[buf ^ 1] + chunk * 1024);
        load_lds16(vbase + (size_t)(chunk * 8 + r8) * 4096 + (size_t)kv0 * 2 +
                       (cb ^ swz),
                   (char*)Vs[buf ^ 1] + chunk * 1024);
      }
    }

    const char* Ksb = (const char*)Ks[buf];
    const char* Vsb = (const char*)Vs[buf];

    // QK^T: s[c] = 16q x 16kv for c-th 16-kv chunk
    f32x4 s[4];
#pragma unroll
    for (int c = 0; c < 4; c++) s[c] = z;
#pragma unroll
    for (int c = 0; c < 4; c++) {
      int kv = c * 16 + li;
#pragma unroll
      for (int f = 0; f < 2; f++) {
        uint4 kf = *(const uint4*)(Ksb + kv * 128 +
                                   ((f * 64 + lg * 16) ^ ((kv & 7) << 4)));
        s[c] = mfma16(qf[f], kf, s[c]);
      }
    }

    // online softmax over 64 cols
    float tm[4], al[4];
#pragma unroll
    for (int j = 0; j < 4; j++)
      tm[j] = fmaxf(fmaxf(s[0][j], s[1][j]), fmaxf(s[2][j], s[3][j]));
#pragma unroll
    for (int off = 8; off >= 1; off >>= 1)
#pragma unroll
      for (int j = 0; j < 4; j++) tm[j] = fmaxf(tm[j], __shfl_xor(tm[j], off));
#pragma unroll
    for (int j = 0; j < 4; j++) {
      float mn = fmaxf(mrun[j], tm[j]);
      al[j] = __expf(mrun[j] - mn);
      mrun[j] = mn;
    }
#pragma unroll
    for (int c = 0; c < 4; c++)
#pragma unroll
      for (int j = 0; j < 4; j++) {
        float p = __expf(s[c][j] - mrun[j]);
        s[c][j] = p;
        int qr = lg * 4 + j;
        *(u16*)(Pw + qr * 128 + ((c * 32 + li * 2) ^ ((qr & 7) << 4))) = f2b(p);
      }
    float rs[4];
#pragma unroll
    for (int j = 0; j < 4; j++)
      rs[j] = (s[0][j] + s[1][j]) + (s[2][j] + s[3][j]);
#pragma unroll
    for (int off = 8; off >= 1; off >>= 1)
#pragma unroll
      for (int j = 0; j < 4; j++) rs[j] += __shfl_xor(rs[j], off);
#pragma unroll
    for (int j = 0; j < 4; j++) lsum[j] = lsum[j] * al[j] + rs[j];

    // PV: rescale o, then o += P @ V^T
#pragma unroll
    for (int db = 0; db < 4; db++)
#pragma unroll
      for (int j = 0; j < 4; j++) o[db][j] *= al[j];

    uint4 pa[2];
#pragma unroll
    for (int kk = 0; kk < 2; kk++)
      pa[kk] = *(const uint4*)(Pw + li * 128 +
                               ((kk * 64 + lg * 16) ^ ((li & 7) << 4)));
#pragma unroll
    for (int db = 0; db < 4; db++) {
      int d = db * 16 + li;
#pragma unroll
      for (int kk = 0; kk < 2; kk++) {
        uint4 vf = *(const uint4*)(Vsb + d * 128 +
                                   ((kk * 64 + lg * 16) ^ ((li & 7) << 4)));
        o[db] = mfma16(pa[kk], vf, o[db]);
      }
    }

    asm volatile("s_waitcnt vmcnt(0)");
    __syncthreads();
    buf ^= 1;
  }

#pragma unroll
  for (int j = 0; j < 4; j++) {
    float rl = 1.0f / lsum[j];
    int n = qb + lg * 4 + j;
#pragma unroll
    for (int db = 0; db < 4; db++)
      out[(size_t)(b * 2048 + n) * 384 + hh * 64 + db * 16 + li] =
          f2b(o[db][j] * rl);
  }
}

// ---------------------------------------------------------------------------
extern "C" void kernel_launch(void* const* d_in, const int* in_sizes, int n_in,
                              void* d_out, int out_size, void* d_ws,
                              size_t ws_size, hipStream_t stream) {
  const float* x      = (const float*)d_in[0];
  const float* ln1_g  = (const float*)d_in[1];
  const float* ln1_b  = (const float*)d_in[2];
  const float* qkv_w  = (const float*)d_in[3];
  const float* qkv_b  = (const float*)d_in[4];
  const float* proj_w = (const float*)d_in[5];
  const float* proj_b = (const float*)d_in[6];
  const float* ln2_g  = (const float*)d_in[7];
  const float* ln2_b  = (const float*)d_in[8];
  const float* fc1_w  = (const float*)d_in[9];
  const float* fc1_b  = (const float*)d_in[10];
  const float* fc2_w  = (const float*)d_in[11];
  const float* fc2_b  = (const float*)d_in[12];
  float* out = (float*)d_out;

  char* p = (char*)d_ws;
  u16* qkvwt  = (u16*)p;  p += (size_t)1152 * 384 * 2;
  u16* projwt = (u16*)p;  p += (size_t)384 * 384 * 2;
  u16* fc1wt  = (u16*)p;  p += (size_t)1536 * 384 * 2;
  u16* fc2wt  = (u16*)p;  p += (size_t)384 * 1536 * 2;
  float* x1   = (float*)p; p += (size_t)8192 * 384 * 4;
  u16* reg1   = (u16*)p;  p += (size_t)8192 * 384 * 2;   // h1 -> aout -> h2
  u16* reg2   = (u16*)p;  p += (size_t)8192 * 1536 * 2;  // q,k,vt -> h3
  u16* qd  = reg2;
  u16* kd  = reg2 + (size_t)24 * 2048 * 64;
  u16* vtd = kd + (size_t)24 * 2048 * 64;
  u16* h3  = reg2;

  convT_k<<<(384 * 1152 + 255) / 256, 256, 0, stream>>>(qkv_w, qkvwt, 384, 1152);
  convT_k<<<(384 * 384 + 255) / 256, 256, 0, stream>>>(proj_w, projwt, 384, 384);
  convT_k<<<(384 * 1536 + 255) / 256, 256, 0, stream>>>(fc1_w, fc1wt, 384, 1536);
  convT_k<<<(1536 * 384 + 255) / 256, 256, 0, stream>>>(fc2_w, fc2wt, 1536, 384);

  ln_k<<<2048, 256, 0, stream>>>(x, ln1_g, ln1_b, reg1);
  gemm_k<2><<<dim3(1152 / BN, 8192 / BM), 256, 0, stream>>>(
      reg1, qkvwt, qkv_b, nullptr, nullptr, 8192, 1152, 384, qd, kd, vtd);
  attn_k<<<dim3(32, 24), 256, 0, stream>>>(qd, kd, vtd, reg1);
  gemm_k<0><<<dim3(384 / BN, 8192 / BM), 256, 0, stream>>>(
      reg1, projwt, proj_b, x, x1, 8192, 384, 384, nullptr, nullptr, nullptr);
  ln_k<<<2048, 256, 0, stream>>>(x1, ln2_g, ln2_b, reg1);
  gemm_k<1><<<dim3(1536 / BN, 8192 / BM), 256, 0, stream>>>(
      reg1, fc1wt, fc1_b, nullptr, h3, 8192, 1536, 384, nullptr, nullptr, nullptr);
  gemm_k<0><<<dim3(384 / BN, 8192 / BM), 256, 0, stream>>>(
      h3, fc2wt, fc2_b, x1, out, 8192, 384, 1536, nullptr, nullptr, nullptr);
}